// Round 11
// baseline (232.804 us; speedup 1.0000x reference)
//
#include <hip/hip_runtime.h>
#include <hip/hip_bf16.h>
#include <math.h>

#define N_NODES 4096
#define NIN     256
#define EMBED   256
#define HEADS   8
#define HEAD_DIM 32
// SCALING * log2(e): folded into Q at projection; leaky_relu commutes with
// positive scaling, so scores come out of QK^T already in exp2-softmax units.
// Fixed-reference softmax: p = exp2(score) (scores bounded ~8.2 -> p <= 2^9).
#define QKSCALE 0.2550610017f

typedef float f32x16 __attribute__((ext_vector_type(16)));
typedef short bf16x8 __attribute__((ext_vector_type(8)));
typedef unsigned int u32x2 __attribute__((ext_vector_type(2)));
typedef unsigned short ushort_t;

static __device__ __forceinline__ ushort_t f2bf(float x) {
  unsigned u = __float_as_uint(x);
  unsigned r = (u + 0x7fffu + ((u >> 16) & 1u)) >> 16;   // RNE
  return (ushort_t)r;
}
static __device__ __forceinline__ float bf2f(ushort_t b) {
  return __uint_as_float((unsigned)b << 16);
}
static __device__ __forceinline__ unsigned cvt_pk_bf16(float lo, float hi) {
  unsigned r;
  asm("v_cvt_pk_bf16_f32 %0, %1, %2" : "=v"(r) : "v"(lo), "v"(hi));
  return r;
}
static __device__ __forceinline__ float fast_exp2(float x) {
  float r;
  asm("v_exp_f32 %0, %1" : "=v"(r) : "v"(x));   // v_exp_f32 IS 2^x
  return r;
}

static __device__ __forceinline__ void half_swap(unsigned a, unsigned b, bool hi,
                                                 unsigned& r0, unsigned& r1) {
#if __has_builtin(__builtin_amdgcn_permlane32_swap)
  u32x2 s = __builtin_amdgcn_permlane32_swap(a, b, false, false);
  r0 = s[0]; r1 = s[1];
#else
  unsigned ax = (unsigned)__shfl_xor((int)a, 32);
  unsigned bx = (unsigned)__shfl_xor((int)b, 32);
  r0 = hi ? bx : a;
  r1 = hi ? b  : ax;
#endif
}

// -------------------- adj -> transposed bitmask --------------------
__global__ __launch_bounds__(256) void pack_adj(const int* __restrict__ adj,
                                                unsigned int* __restrict__ bitsT) {
  int q = blockIdx.x;
  int wave = threadIdx.x >> 6, lane = threadIdx.x & 63;
  #pragma unroll
  for (int i = 0; i < 16; ++i) {
    int g64 = wave * 16 + i;
    int k = g64 * 64 + lane;
    int v = adj[(size_t)q * N_NODES + k];
    unsigned long long b = __ballot(v > 0);
    if (lane == 0) {
      bitsT[(size_t)(2 * g64)     * N_NODES + q] = (unsigned int)b;
      bitsT[(size_t)(2 * g64 + 1) * N_NODES + q] = (unsigned int)(b >> 32);
    }
  }
}

// -------------------- fp32 -> bf16 hi/lo splits --------------------
__global__ __launch_bounds__(256) void split_x(const float* __restrict__ x,
    ushort_t* __restrict__ xh, ushort_t* __restrict__ xl) {
  int idx = blockIdx.x * 256 + threadIdx.x;
  float4 v = ((const float4*)x)[idx];
  union { ushort_t u[4]; unsigned long long q; } hb, lb;
  float c[4] = {v.x, v.y, v.z, v.w};
  #pragma unroll
  for (int j = 0; j < 4; ++j) {
    hb.u[j] = f2bf(c[j]);
    lb.u[j] = f2bf(c[j] - bf2f(hb.u[j]));
  }
  *(unsigned long long*)(xh + (size_t)idx * 4) = hb.q;
  *(unsigned long long*)(xl + (size_t)idx * 4) = lb.q;
}

__global__ __launch_bounds__(256) void split_w(const float* __restrict__ Wq,
    const float* __restrict__ Wk, const float* __restrict__ Wv,
    ushort_t* __restrict__ Wh, ushort_t* __restrict__ Wl) {
  int idx = blockIdx.x * 256 + threadIdx.x;
  int row = idx >> 6;
  const float* src = row < 256 ? Wq : (row < 512 ? Wk : Wv);
  float4 v = ((const float4*)(src + (size_t)(row & 255) * NIN))[idx & 63];
  union { ushort_t u[4]; unsigned long long q; } hb, lb;
  float c[4] = {v.x, v.y, v.z, v.w};
  #pragma unroll
  for (int j = 0; j < 4; ++j) {
    hb.u[j] = f2bf(c[j]);
    lb.u[j] = f2bf(c[j] - bf2f(hb.u[j]));
  }
  *(unsigned long long*)(Wh + (size_t)idx * 4) = hb.q;
  *(unsigned long long*)(Wl + (size_t)idx * 4) = lb.q;
}

// -------------------- QKV projection via MFMA (bf16x3) --------------------
__global__ __launch_bounds__(256) void qkv_mfma(
    const ushort_t* __restrict__ xh, const ushort_t* __restrict__ xl,
    const ushort_t* __restrict__ Wh, const ushort_t* __restrict__ Wl,
    const float* __restrict__ bq, const float* __restrict__ bk,
    const float* __restrict__ bv,
    ushort_t* __restrict__ Qph, ushort_t* __restrict__ Qpl,
    ushort_t* __restrict__ Kph, ushort_t* __restrict__ Kpl,
    float* __restrict__ Vo) {
  __shared__ float ts[4][32][33];
  int lane = threadIdx.x & 63, w = threadIdx.x >> 6;
  int c = lane & 31, g = lane >> 5;
  int mt = blockIdx.x;
  int et = blockIdx.y * 4 + w;

  const ushort_t* wha = Wh + (size_t)(et * 32 + c) * NIN + g * 8;
  const ushort_t* wla = Wl + (size_t)(et * 32 + c) * NIN + g * 8;
  const ushort_t* xha = xh + (size_t)(mt * 32 + c) * NIN + g * 8;
  const ushort_t* xla = xl + (size_t)(mt * 32 + c) * NIN + g * 8;

  f32x16 acc;
  #pragma unroll
  for (int i = 0; i < 16; ++i) acc[i] = 0.f;
  #pragma unroll 4
  for (int s = 0; s < 16; ++s) {
    bf16x8 ah = *(const bf16x8*)(wha + s * 16);
    bf16x8 al = *(const bf16x8*)(wla + s * 16);
    bf16x8 bh = *(const bf16x8*)(xha + s * 16);
    bf16x8 bl = *(const bf16x8*)(xla + s * 16);
    acc = __builtin_amdgcn_mfma_f32_32x32x16_bf16(ah, bh, acc, 0, 0, 0);
    acc = __builtin_amdgcn_mfma_f32_32x32x16_bf16(ah, bl, acc, 0, 0, 0);
    acc = __builtin_amdgcn_mfma_f32_32x32x16_bf16(al, bh, acc, 0, 0, 0);
  }

  int mat = et >> 3, h = et & 7;
  const float* bias = mat == 0 ? bq : (mat == 1 ? bk : bv);
  float scl = mat == 0 ? QKSCALE : 1.0f;
  #pragma unroll
  for (int r = 0; r < 16; ++r) {
    int erow = (r & 3) + 8 * (r >> 2) + 4 * g;
    ts[w][erow][c] = (acc[r] + bias[h * 32 + erow]) * scl;
  }
  if (mat < 2) {
    ushort_t* Ph = mat == 0 ? Qph : Kph;
    ushort_t* Pl = mat == 0 ? Qpl : Kpl;
    #pragma unroll
    for (int sl = 0; sl < 2; ++sl) {
      union { ushort_t u[8]; bf16x8 v; } hbv, lbv;
      #pragma unroll
      for (int j = 0; j < 8; ++j) {
        float v = ts[w][sl * 16 + g * 8 + j][c];
        hbv.u[j] = f2bf(v);
        lbv.u[j] = f2bf(v - bf2f(hbv.u[j]));
      }
      size_t dst = (((size_t)(h * 128 + mt) * 2 + sl) * 64 + lane) * 8;
      *(bf16x8*)(Ph + dst) = hbv.v;
      *(bf16x8*)(Pl + dst) = lbv.v;
    }
  } else {
    #pragma unroll
    for (int i = 0; i < 16; ++i) {
      int flat = lane + i * 64;
      int ml = flat >> 5, el = flat & 31;
      Vo[(size_t)(mt * 32 + ml) * EMBED + h * 32 + el] = ts[w][el][ml];
    }
  }
}

// -------------------- softmax(V) over head dim + fragment pack --------------------
__global__ __launch_bounds__(256) void sv_softmax_t(const float* __restrict__ V,
    ushort_t* __restrict__ SVph, ushort_t* __restrict__ SVpl) {
  __shared__ float sv[32][257];
  int tile = blockIdx.x;
  int n0 = tile * 32;
  int t = threadIdx.x;
  for (int i = 0; i < 32; ++i) sv[i][t] = V[(size_t)(n0 + i) * EMBED + t];
  __syncthreads();
  int node = t & 31, hh = t >> 5;
  float mx = -INFINITY;
  #pragma unroll
  for (int d = 0; d < 32; ++d) mx = fmaxf(mx, sv[node][hh * 32 + d]);
  float s = 0.f;
  #pragma unroll
  for (int d = 0; d < 32; ++d) s += __expf(sv[node][hh * 32 + d] - mx);
  float inv = 1.f / s;
  #pragma unroll
  for (int d = 0; d < 32; ++d)
    sv[node][hh * 32 + d] = __expf(sv[node][hh * 32 + d] - mx) * inv;
  __syncthreads();
  #pragma unroll
  for (int i = 0; i < 4; ++i) {
    int fid = t + i * 256;
    int h = fid >> 7, sl = (fid >> 6) & 1, ln = fid & 63;
    int g = ln >> 5, c = ln & 31;
    union { ushort_t u[8]; bf16x8 v; } hb, lb;
    #pragma unroll
    for (int j = 0; j < 8; ++j) {
      int n = sl * 16 + g * 8 + j;
      float v = sv[n][h * 32 + c];
      hb.u[j] = f2bf(v);
      lb.u[j] = f2bf(v - bf2f(hb.u[j]));
    }
    size_t dst = (((size_t)(h * 128 + tile) * 2 + sl) * 64 + ln) * 8;
    *(bf16x8*)(SVph + dst) = hb.v;
    *(bf16x8*)(SVpl + dst) = lb.v;
  }
}

// -------------------- fused masked flash attention, LDS-shared K/SV --------------------
// 256 blocks (h = bid&7 pins head to XCD), 8 waves = 4 q-waves x 2 kv-groups.
// Each kv-group's K/SV tile staged once in LDS per step, consumed by 4 waves.
// Double-buffered, reg-staged: barrier -> issue next loads -> compute -> ds_write.
__global__ __launch_bounds__(512) void attn32(
    const ushort_t* __restrict__ Qph, const ushort_t* __restrict__ Qpl,
    const ushort_t* __restrict__ Kph, const ushort_t* __restrict__ Kpl,
    const ushort_t* __restrict__ SVph, const ushort_t* __restrict__ SVpl,
    const unsigned int* __restrict__ bitsT, const float* __restrict__ V,
    float* __restrict__ out) {
  __shared__ ushort_t stage[2][2][4][1024];  // [dbuf][kvgrp][Kh,Kl,SVh,SVl][2KB]
  __shared__ float o_s[4][32][32];           // kv-group-1 partial O
  __shared__ float l_s[8][32];

  int lane = threadIdx.x & 63;
  int wid  = threadIdx.x >> 6;     // 0..7
  int col  = lane & 31;
  int g    = lane >> 5;
  bool hi  = (g != 0);
  int wq   = wid & 3;              // q-wave 0..3
  int wkc  = wid >> 2;             // kv-group 0..1 (compute identity)
  int bid  = blockIdx.x;
  int h    = bid & 7;              // pins head to XCD (bid%8 round-robin)
  int qblk = bid >> 3;             // 0..31
  int qt_w = qblk * 4 + wq;
  int q    = qt_w * 32 + col;

  // staging duty: wave (sw, sc) stages component sc of kv-group sw
  int sw = wid >> 2, sc = wid & 3;
  const ushort_t* mysrc =
      (sc == 0 ? Kph : sc == 1 ? Kpl : sc == 2 ? SVph : SVpl) +
      (size_t)(h * 128) * 1024;

  // Q fragments (register-resident)
  size_t qb = (size_t)(h * 128 + qt_w) * 1024 + lane * 8;
  bf16x8 qbh0 = *(const bf16x8*)(Qph + qb);
  bf16x8 qbh1 = *(const bf16x8*)(Qph + qb + 512);
  bf16x8 qbl0 = *(const bf16x8*)(Qpl + qb);
  bf16x8 qbl1 = *(const bf16x8*)(Qpl + qb + 512);

  f32x16 o;
  #pragma unroll
  for (int i = 0; i < 16; ++i) o[i] = 0.f;
  float lsum = 0.f;

  // prologue: stage tile 0 of this kv-group into buf 0
  {
    const ushort_t* s = mysrc + (size_t)(sw * 64) * 1024;
    bf16x8 p0 = *(const bf16x8*)(s + lane * 8);
    bf16x8 p1 = *(const bf16x8*)(s + 512 + lane * 8);
    ushort_t* d = &stage[0][sw][sc][0];
    *(bf16x8*)(d + lane * 8) = p0;
    *(bf16x8*)(d + 512 + lane * 8) = p1;
  }
  int cur = 0;

  for (int t = 0; t < 64; ++t) {
    __syncthreads();                       // stage[cur] visible to all

    // issue next tile's global loads (latency hidden by compute below)
    bf16x8 r0, r1;
    if (t < 63) {
      const ushort_t* s = mysrc + (size_t)(sw * 64 + t + 1) * 1024;
      r0 = *(const bf16x8*)(s + lane * 8);
      r1 = *(const bf16x8*)(s + 512 + lane * 8);
    }

    int tile = wkc * 64 + t;
    const ushort_t* kh  = &stage[cur][wkc][0][0];
    const ushort_t* kl  = &stage[cur][wkc][1][0];
    const ushort_t* shv = &stage[cur][wkc][2][0];
    const ushort_t* slv = &stage[cur][wkc][3][0];

    bf16x8 kah0 = *(const bf16x8*)(kh + lane * 8);
    bf16x8 kah1 = *(const bf16x8*)(kh + 512 + lane * 8);
    bf16x8 kal0 = *(const bf16x8*)(kl + lane * 8);
    bf16x8 kal1 = *(const bf16x8*)(kl + 512 + lane * 8);
    unsigned int mw = bitsT[(size_t)tile * N_NODES + q] >> (4 * g);

    f32x16 st;
    #pragma unroll
    for (int i = 0; i < 16; ++i) st[i] = 0.f;
    __builtin_amdgcn_s_setprio(1);
    st = __builtin_amdgcn_mfma_f32_32x32x16_bf16(kah0, qbh0, st, 0, 0, 0);
    st = __builtin_amdgcn_mfma_f32_32x32x16_bf16(kah1, qbh1, st, 0, 0, 0);
    st = __builtin_amdgcn_mfma_f32_32x32x16_bf16(kah0, qbl0, st, 0, 0, 0);
    st = __builtin_amdgcn_mfma_f32_32x32x16_bf16(kah1, qbl1, st, 0, 0, 0);
    st = __builtin_amdgcn_mfma_f32_32x32x16_bf16(kal0, qbh0, st, 0, 0, 0);
    st = __builtin_amdgcn_mfma_f32_32x32x16_bf16(kal1, qbh1, st, 0, 0, 0);
    __builtin_amdgcn_s_setprio(0);

    // leaky_relu (scale pre-folded) + mask + fixed-reference exp2
    float p[16];
    #pragma unroll
    for (int r = 0; r < 16; ++r) {
      float v = st[r];
      float pe = fast_exp2(fmaxf(v, 0.01f * v));
      bool on = (mw >> ((r & 3) + 8 * (r >> 2))) & 1;
      float pv = on ? pe : 0.f;
      p[r] = pv;
      lsum += pv;
    }

    // P -> bf16 A-fragments via cvt_pk + half_swap
    unsigned int w[8];
    #pragma unroll
    for (int i = 0; i < 8; ++i) w[i] = cvt_pk_bf16(p[2 * i], p[2 * i + 1]);
    unsigned s02a, s02b, s13a, s13b, s46a, s46b, s57a, s57b;
    half_swap(w[0], w[2], hi, s02a, s02b);
    half_swap(w[1], w[3], hi, s13a, s13b);
    half_swap(w[4], w[6], hi, s46a, s46b);
    half_swap(w[5], w[7], hi, s57a, s57b);
    union { unsigned int u[4]; bf16x8 v; } pa0, pa1;
    pa0.u[0] = s02a; pa0.u[1] = s13a; pa0.u[2] = s02b; pa0.u[3] = s13b;
    pa1.u[0] = s46a; pa1.u[1] = s57a; pa1.u[2] = s46b; pa1.u[3] = s57b;

    bf16x8 svh0 = *(const bf16x8*)(shv + lane * 8);
    bf16x8 svh1 = *(const bf16x8*)(shv + 512 + lane * 8);
    bf16x8 svl0 = *(const bf16x8*)(slv + lane * 8);
    bf16x8 svl1 = *(const bf16x8*)(slv + 512 + lane * 8);
    __builtin_amdgcn_s_setprio(1);
    o = __builtin_amdgcn_mfma_f32_32x32x16_bf16(pa0.v, svh0, o, 0, 0, 0);
    o = __builtin_amdgcn_mfma_f32_32x32x16_bf16(pa1.v, svh1, o, 0, 0, 0);
    o = __builtin_amdgcn_mfma_f32_32x32x16_bf16(pa0.v, svl0, o, 0, 0, 0);
    o = __builtin_amdgcn_mfma_f32_32x32x16_bf16(pa1.v, svl1, o, 0, 0, 0);
    __builtin_amdgcn_s_setprio(0);

    // write next tile into the other buffer (vmcnt wait happens here, late)
    if (t < 63) {
      ushort_t* d = &stage[cur ^ 1][sw][sc][0];
      *(bf16x8*)(d + lane * 8) = r0;
      *(bf16x8*)(d + 512 + lane * 8) = r1;
      cur ^= 1;
    }
  }

  // ---- merge kv-group partials (plain sums, fixed softmax reference) ----
  float Lt = lsum + __shfl_xor(lsum, 32);
  if (lane < 32) l_s[wid][col] = Lt;
  if (wkc == 1) {
    #pragma unroll
    for (int r = 0; r < 16; ++r) {
      int qr = (r & 3) + 8 * (r >> 2) + 4 * g;
      o_s[wq][qr][col] = o[r];
    }
  }
  __syncthreads();
  if (wkc == 0) {
    #pragma unroll
    for (int r = 0; r < 16; ++r) {
      int qr = (r & 3) + 8 * (r >> 2) + 4 * g;
      float O = o[r] + o_s[wq][qr][col];
      float L = l_s[wq][qr] + l_s[4 + wq][qr];
      int qg = qblk * 128 + wq * 32 + qr;
      float vv = V[(size_t)qg * EMBED + h * 32 + col];
      out[((size_t)h * N_NODES + qg) * HEAD_DIM + col] = vv - O / L;
    }
  }
}

extern "C" void kernel_launch(void* const* d_in, const int* in_sizes, int n_in,
                              void* d_out, int out_size, void* d_ws, size_t ws_size,
                              hipStream_t stream) {
  const float* x   = (const float*)d_in[0];
  const int*   adj = (const int*)d_in[1];
  const float* Wq  = (const float*)d_in[2];
  const float* bq  = (const float*)d_in[3];
  const float* Wk  = (const float*)d_in[4];
  const float* bk  = (const float*)d_in[5];
  const float* Wv  = (const float*)d_in[6];
  const float* bv  = (const float*)d_in[7];
  float* out = (float*)d_out;

  char* ws = (char*)d_ws;
  ushort_t*     Qph  = (ushort_t*)(ws);                          // 2 MB
  ushort_t*     Qpl  = (ushort_t*)(ws + ((size_t)2  << 20));     // 2 MB
  ushort_t*     Kph  = (ushort_t*)(ws + ((size_t)4  << 20));     // 2 MB
  ushort_t*     Kpl  = (ushort_t*)(ws + ((size_t)6  << 20));     // 2 MB
  ushort_t*     SVph = (ushort_t*)(ws + ((size_t)8  << 20));     // 2 MB
  ushort_t*     SVpl = (ushort_t*)(ws + ((size_t)10 << 20));     // 2 MB
  float*        V    = (float*)(ws + ((size_t)12 << 20));        // 4 MB
  unsigned int* bits = (unsigned int*)(ws + ((size_t)16 << 20)); // 2 MB
  ushort_t*     xh   = (ushort_t*)(ws + ((size_t)18 << 20));     // 2 MB
  ushort_t*     xl   = (ushort_t*)(ws + ((size_t)20 << 20));     // 2 MB
  ushort_t*     Wh   = (ushort_t*)(ws + ((size_t)22 << 20));           // 384 KB
  ushort_t*     Wl   = (ushort_t*)(ws + ((size_t)22 << 20) + 393216);  // 384 KB

  pack_adj<<<dim3(N_NODES), 256, 0, stream>>>(adj, bits);
  split_x<<<dim3((N_NODES * NIN / 4) / 256), 256, 0, stream>>>(x, xh, xl);
  split_w<<<dim3((768 * NIN / 4) / 256), 256, 0, stream>>>(Wq, Wk, Wv, Wh, Wl);
  qkv_mfma<<<dim3(N_NODES / 32, 6), 256, 0, stream>>>(
      xh, xl, Wh, Wl, bq, bk, bv, Qph, Qpl, Kph, Kpl, V);
  sv_softmax_t<<<dim3(N_NODES / 32), 256, 0, stream>>>(V, SVph, SVpl);
  attn32<<<dim3(256), 512, 0, stream>>>(
      Qph, Qpl, Kph, Kpl, SVph, SVpl, bits, V, out);
}

// Round 14
// 207.475 us; speedup vs baseline: 1.1221x; 1.1221x over previous
//
#include <hip/hip_runtime.h>
#include <hip/hip_bf16.h>
#include <math.h>

#define N_NODES 4096
#define NIN     256
#define EMBED   256
#define HEADS   8
#define HEAD_DIM 32
// SCALING * log2(e): folded into Q at projection; leaky_relu commutes with
// positive scaling, so scores come out of QK^T already in exp2-softmax units.
// Fixed-reference softmax: p = exp2(score) (scores bounded ~8.2 -> p <= 2^9).
#define QKSCALE 0.2550610017f

typedef float f32x16 __attribute__((ext_vector_type(16)));
typedef short bf16x8 __attribute__((ext_vector_type(8)));
typedef unsigned int u32x2 __attribute__((ext_vector_type(2)));
typedef unsigned short ushort_t;

static __device__ __forceinline__ ushort_t f2bf(float x) {
  unsigned u = __float_as_uint(x);
  unsigned r = (u + 0x7fffu + ((u >> 16) & 1u)) >> 16;   // RNE
  return (ushort_t)r;
}
static __device__ __forceinline__ float bf2f(ushort_t b) {
  return __uint_as_float((unsigned)b << 16);
}
static __device__ __forceinline__ unsigned cvt_pk_bf16(float lo, float hi) {
  unsigned r;
  asm("v_cvt_pk_bf16_f32 %0, %1, %2" : "=v"(r) : "v"(lo), "v"(hi));
  return r;
}
static __device__ __forceinline__ float fast_exp2(float x) {
  float r;
  asm("v_exp_f32 %0, %1" : "=v"(r) : "v"(x));   // v_exp_f32 IS 2^x
  return r;
}

static __device__ __forceinline__ void half_swap(unsigned a, unsigned b, bool hi,
                                                 unsigned& r0, unsigned& r1) {
#if __has_builtin(__builtin_amdgcn_permlane32_swap)
  u32x2 s = __builtin_amdgcn_permlane32_swap(a, b, false, false);
  r0 = s[0]; r1 = s[1];
#else
  unsigned ax = (unsigned)__shfl_xor((int)a, 32);
  unsigned bx = (unsigned)__shfl_xor((int)b, 32);
  r0 = hi ? bx : a;
  r1 = hi ? b  : ax;
#endif
}

// -------------------- adj -> transposed bitmask --------------------
__global__ __launch_bounds__(256) void pack_adj(const int* __restrict__ adj,
                                                unsigned int* __restrict__ bitsT) {
  int q = blockIdx.x;
  int wave = threadIdx.x >> 6, lane = threadIdx.x & 63;
  #pragma unroll
  for (int i = 0; i < 16; ++i) {
    int g64 = wave * 16 + i;
    int k = g64 * 64 + lane;
    int v = adj[(size_t)q * N_NODES + k];
    unsigned long long b = __ballot(v > 0);
    if (lane == 0) {
      bitsT[(size_t)(2 * g64)     * N_NODES + q] = (unsigned int)b;
      bitsT[(size_t)(2 * g64 + 1) * N_NODES + q] = (unsigned int)(b >> 32);
    }
  }
}

// -------------------- fp32 -> bf16 hi/lo splits, FRAGMENT-PACKED --------------------
// x packed as the B-operand layout qkv_mfma consumes:
//   xp[(mt*16 + s)*512 + (g*32 + c)*8 + j] = x[mt*32 + c][s*16 + g*8 + j]
__global__ __launch_bounds__(256) void split_x(const float* __restrict__ x,
    ushort_t* __restrict__ xph, ushort_t* __restrict__ xpl) {
  int slot = blockIdx.x * 256 + threadIdx.x;   // 0..131071 (8 elems each)
  int m = slot >> 5, col8 = slot & 31;
  const float4* src = (const float4*)(x + (size_t)m * NIN + col8 * 8);
  float4 a = src[0], b = src[1];
  float c[8] = {a.x, a.y, a.z, a.w, b.x, b.y, b.z, b.w};
  union { ushort_t u[8]; bf16x8 v; } hb, lb;
  #pragma unroll
  for (int j = 0; j < 8; ++j) {
    hb.u[j] = f2bf(c[j]);
    lb.u[j] = f2bf(c[j] - bf2f(hb.u[j]));
  }
  size_t dst = ((((size_t)(m >> 5) * 16 + (col8 >> 1)) * 64) +
                (col8 & 1) * 32 + (m & 31)) * 8;
  *(bf16x8*)(xph + dst) = hb.v;
  *(bf16x8*)(xpl + dst) = lb.v;
}

// W concat [768][256] packed as the A-operand layout:
//   wp[(et*16 + s)*512 + (g*32 + c)*8 + j] = Wcat[et*32 + c][s*16 + g*8 + j]
__global__ __launch_bounds__(256) void split_w(const float* __restrict__ Wq,
    const float* __restrict__ Wk, const float* __restrict__ Wv,
    ushort_t* __restrict__ Wph, ushort_t* __restrict__ Wpl) {
  int slot = blockIdx.x * 256 + threadIdx.x;   // 0..24575
  int r = slot >> 5, col8 = slot & 31;
  const float* src = r < 256 ? Wq : (r < 512 ? Wk : Wv);
  const float4* s4 = (const float4*)(src + (size_t)(r & 255) * NIN + col8 * 8);
  float4 a = s4[0], b = s4[1];
  float c[8] = {a.x, a.y, a.z, a.w, b.x, b.y, b.z, b.w};
  union { ushort_t u[8]; bf16x8 v; } hb, lb;
  #pragma unroll
  for (int j = 0; j < 8; ++j) {
    hb.u[j] = f2bf(c[j]);
    lb.u[j] = f2bf(c[j] - bf2f(hb.u[j]));
  }
  size_t dst = ((((size_t)(r >> 5) * 16 + (col8 >> 1)) * 64) +
                (col8 & 1) * 32 + (r & 31)) * 8;
  *(bf16x8*)(Wph + dst) = hb.v;
  *(bf16x8*)(Wpl + dst) = lb.v;
}

// -------------------- QKV projection via MFMA (bf16x3, coalesced frags) ------------
// One wave = one 32x32 output tile: D[e][m] = mfma(A=W rows, B=x rows).
// All operand loads are lane-consecutive 16B (packed layouts above).
__global__ __launch_bounds__(256) void qkv_mfma(
    const ushort_t* __restrict__ xph, const ushort_t* __restrict__ xpl,
    const ushort_t* __restrict__ Wph, const ushort_t* __restrict__ Wpl,
    const float* __restrict__ bq, const float* __restrict__ bk,
    const float* __restrict__ bv,
    ushort_t* __restrict__ Qph, ushort_t* __restrict__ Qpl,
    ushort_t* __restrict__ Kph, ushort_t* __restrict__ Kpl,
    float* __restrict__ Vo) {
  __shared__ float ts[4][32][33];
  int lane = threadIdx.x & 63, w = threadIdx.x >> 6;
  int c = lane & 31, g = lane >> 5;
  int mt = blockIdx.x;
  int et = blockIdx.y * 4 + w;

  const ushort_t* wa_h = Wph + (size_t)et * 8192 + lane * 8;
  const ushort_t* wa_l = Wpl + (size_t)et * 8192 + lane * 8;
  const ushort_t* xb_h = xph + (size_t)mt * 8192 + lane * 8;
  const ushort_t* xb_l = xpl + (size_t)mt * 8192 + lane * 8;

  f32x16 acc;
  #pragma unroll
  for (int i = 0; i < 16; ++i) acc[i] = 0.f;
  #pragma unroll 4
  for (int s = 0; s < 16; ++s) {
    bf16x8 ah = *(const bf16x8*)(wa_h + s * 512);
    bf16x8 al = *(const bf16x8*)(wa_l + s * 512);
    bf16x8 bh = *(const bf16x8*)(xb_h + s * 512);
    bf16x8 bl = *(const bf16x8*)(xb_l + s * 512);
    acc = __builtin_amdgcn_mfma_f32_32x32x16_bf16(ah, bh, acc, 0, 0, 0);
    acc = __builtin_amdgcn_mfma_f32_32x32x16_bf16(ah, bl, acc, 0, 0, 0);
    acc = __builtin_amdgcn_mfma_f32_32x32x16_bf16(al, bh, acc, 0, 0, 0);
  }

  int mat = et >> 3, h = et & 7;
  const float* bias = mat == 0 ? bq : (mat == 1 ? bk : bv);
  float scl = mat == 0 ? QKSCALE : 1.0f;
  #pragma unroll
  for (int r = 0; r < 16; ++r) {
    int erow = (r & 3) + 8 * (r >> 2) + 4 * g;
    ts[w][erow][c] = (acc[r] + bias[h * 32 + erow]) * scl;
  }
  // same-wave LDS write->read transpose (compiler inserts lgkmcnt wait)
  if (mat < 2) {
    ushort_t* Ph = mat == 0 ? Qph : Kph;
    ushort_t* Pl = mat == 0 ? Qpl : Kpl;
    #pragma unroll
    for (int sl = 0; sl < 2; ++sl) {
      union { ushort_t u[8]; bf16x8 v; } hbv, lbv;
      #pragma unroll
      for (int j = 0; j < 8; ++j) {
        float v = ts[w][sl * 16 + g * 8 + j][c];
        hbv.u[j] = f2bf(v);
        lbv.u[j] = f2bf(v - bf2f(hbv.u[j]));
      }
      size_t dst = (((size_t)(h * 128 + mt) * 2 + sl) * 64 + lane) * 8;
      *(bf16x8*)(Ph + dst) = hbv.v;
      *(bf16x8*)(Pl + dst) = lbv.v;
    }
  } else {
    #pragma unroll
    for (int i = 0; i < 16; ++i) {
      int flat = lane + i * 64;
      int ml = flat >> 5, el = flat & 31;
      Vo[(size_t)(mt * 32 + ml) * EMBED + h * 32 + el] = ts[w][el][ml];
    }
  }
}

// -------------------- softmax(V) over head dim + fragment pack --------------------
__global__ __launch_bounds__(256) void sv_softmax_t(const float* __restrict__ V,
    ushort_t* __restrict__ SVph, ushort_t* __restrict__ SVpl) {
  __shared__ float sv[32][257];
  int tile = blockIdx.x;
  int n0 = tile * 32;
  int t = threadIdx.x;
  for (int i = 0; i < 32; ++i) sv[i][t] = V[(size_t)(n0 + i) * EMBED + t];
  __syncthreads();
  int node = t & 31, hh = t >> 5;
  float mx = -INFINITY;
  #pragma unroll
  for (int d = 0; d < 32; ++d) mx = fmaxf(mx, sv[node][hh * 32 + d]);
  float s = 0.f;
  #pragma unroll
  for (int d = 0; d < 32; ++d) s += __expf(sv[node][hh * 32 + d] - mx);
  float inv = 1.f / s;
  #pragma unroll
  for (int d = 0; d < 32; ++d)
    sv[node][hh * 32 + d] = __expf(sv[node][hh * 32 + d] - mx) * inv;
  __syncthreads();
  #pragma unroll
  for (int i = 0; i < 4; ++i) {
    int fid = t + i * 256;
    int h = fid >> 7, sl = (fid >> 6) & 1, ln = fid & 63;
    int g = ln >> 5, c = ln & 31;
    union { ushort_t u[8]; bf16x8 v; } hb, lb;
    #pragma unroll
    for (int j = 0; j < 8; ++j) {
      int n = sl * 16 + g * 8 + j;
      float v = sv[n][h * 32 + c];
      hb.u[j] = f2bf(v);
      lb.u[j] = f2bf(v - bf2f(hb.u[j]));
    }
    size_t dst = (((size_t)(h * 128 + tile) * 2 + sl) * 64 + ln) * 8;
    *(bf16x8*)(SVph + dst) = hb.v;
    *(bf16x8*)(SVpl + dst) = lb.v;
  }
}

// -------------------- fused masked flash attention, MFMA 32x32x16 --------------------
// (Round-10 proven structure: 1024 blocks, 8 waves each own 1/8 of kv, LDS merge.)
__global__ __launch_bounds__(512) void attn32(
    const ushort_t* __restrict__ Qph, const ushort_t* __restrict__ Qpl,
    const ushort_t* __restrict__ Kph, const ushort_t* __restrict__ Kpl,
    const ushort_t* __restrict__ SVph, const ushort_t* __restrict__ SVpl,
    const unsigned int* __restrict__ bitsT, const float* __restrict__ V,
    float* __restrict__ out) {
  __shared__ float o_s[8][32][32];
  __shared__ float l_s[8][32];

  int lane = threadIdx.x & 63;
  int wid  = threadIdx.x >> 6;   // 0..7
  int col  = lane & 31;          // q (S^T out) / d (PV out)
  int g    = lane >> 5;
  bool hi  = (g != 0);
  int h  = blockIdx.y;
  int qt = blockIdx.x;
  int q0 = qt * 32;
  int q  = q0 + col;

  size_t qbase = ((size_t)(h * 128 + qt) * 2) * 512 + lane * 8;
  bf16x8 qbh0 = *(const bf16x8*)(Qph + qbase);
  bf16x8 qbh1 = *(const bf16x8*)(Qph + qbase + 512);
  bf16x8 qbl0 = *(const bf16x8*)(Qpl + qbase);
  bf16x8 qbl1 = *(const bf16x8*)(Qpl + qbase + 512);

  f32x16 o;
  #pragma unroll
  for (int i = 0; i < 16; ++i) o[i] = 0.f;
  float lsum = 0.f;

  #pragma unroll 2
  for (int t = 0; t < 16; ++t) {
    int tile = wid * 16 + t;            // this wave's kv eighth
    size_t kb = ((size_t)(h * 128 + tile) * 2) * 512 + lane * 8;
    bf16x8 kah0 = *(const bf16x8*)(Kph + kb);
    bf16x8 kah1 = *(const bf16x8*)(Kph + kb + 512);
    bf16x8 kal0 = *(const bf16x8*)(Kpl + kb);
    bf16x8 kal1 = *(const bf16x8*)(Kpl + kb + 512);
    unsigned int mw = bitsT[(size_t)tile * N_NODES + q] >> (4 * g);

    f32x16 st;
    #pragma unroll
    for (int i = 0; i < 16; ++i) st[i] = 0.f;
    __builtin_amdgcn_s_setprio(1);
    st = __builtin_amdgcn_mfma_f32_32x32x16_bf16(kah0, qbh0, st, 0, 0, 0);
    st = __builtin_amdgcn_mfma_f32_32x32x16_bf16(kah1, qbh1, st, 0, 0, 0);
    st = __builtin_amdgcn_mfma_f32_32x32x16_bf16(kah0, qbl0, st, 0, 0, 0);
    st = __builtin_amdgcn_mfma_f32_32x32x16_bf16(kah1, qbl1, st, 0, 0, 0);
    st = __builtin_amdgcn_mfma_f32_32x32x16_bf16(kal0, qbh0, st, 0, 0, 0);
    st = __builtin_amdgcn_mfma_f32_32x32x16_bf16(kal1, qbh1, st, 0, 0, 0);
    __builtin_amdgcn_s_setprio(0);

    // leaky_relu (scale pre-folded) + mask + fixed-reference exp2
    float p[16];
    #pragma unroll
    for (int r = 0; r < 16; ++r) {
      float v = st[r];
      float pe = fast_exp2(fmaxf(v, 0.01f * v));
      bool on = (mw >> ((r & 3) + 8 * (r >> 2))) & 1;
      float pv = on ? pe : 0.f;
      p[r] = pv;
      lsum += pv;
    }

    // P -> bf16 A-fragments via cvt_pk + half_swap
    unsigned int w[8];
    #pragma unroll
    for (int i = 0; i < 8; ++i) w[i] = cvt_pk_bf16(p[2 * i], p[2 * i + 1]);
    unsigned s02a, s02b, s13a, s13b, s46a, s46b, s57a, s57b;
    half_swap(w[0], w[2], hi, s02a, s02b);
    half_swap(w[1], w[3], hi, s13a, s13b);
    half_swap(w[4], w[6], hi, s46a, s46b);
    half_swap(w[5], w[7], hi, s57a, s57b);
    union { unsigned int u[4]; bf16x8 v; } pa0, pa1;
    pa0.u[0] = s02a; pa0.u[1] = s13a; pa0.u[2] = s02b; pa0.u[3] = s13b;
    pa1.u[0] = s46a; pa1.u[1] = s57a; pa1.u[2] = s46b; pa1.u[3] = s57b;

    size_t sb = ((size_t)(h * 128 + tile) * 2) * 512 + lane * 8;
    bf16x8 svh0 = *(const bf16x8*)(SVph + sb);
    bf16x8 svh1 = *(const bf16x8*)(SVph + sb + 512);
    bf16x8 svl0 = *(const bf16x8*)(SVpl + sb);
    bf16x8 svl1 = *(const bf16x8*)(SVpl + sb + 512);
    __builtin_amdgcn_s_setprio(1);
    o = __builtin_amdgcn_mfma_f32_32x32x16_bf16(pa0.v, svh0, o, 0, 0, 0);
    o = __builtin_amdgcn_mfma_f32_32x32x16_bf16(pa1.v, svh1, o, 0, 0, 0);
    o = __builtin_amdgcn_mfma_f32_32x32x16_bf16(pa0.v, svl0, o, 0, 0, 0);
    o = __builtin_amdgcn_mfma_f32_32x32x16_bf16(pa1.v, svl1, o, 0, 0, 0);
    __builtin_amdgcn_s_setprio(0);
  }

  // ---- block-level merge: plain sums (shared fixed softmax reference) ----
  float Lt = lsum + __shfl_xor(lsum, 32);
  #pragma unroll
  for (int r = 0; r < 16; ++r) {
    int ql = (r & 3) + 8 * (r >> 2) + 4 * g;
    o_s[wid][ql][col] = o[r];
  }
  if (lane < 32) l_s[wid][col] = Lt;
  __syncthreads();

  #pragma unroll
  for (int i = 0; i < 2; ++i) {
    int idx = threadIdx.x + i * 512;    // 0..1023 = (qloc, d)
    int ql = idx >> 5, d = idx & 31;
    float O = 0.f, L = 0.f;
    #pragma unroll
    for (int w2 = 0; w2 < 8; ++w2) {
      O += o_s[w2][ql][d];
      L += l_s[w2][ql];
    }
    int qq = q0 + ql;
    out[((size_t)h * N_NODES + qq) * HEAD_DIM + d] =
        V[(size_t)qq * EMBED + h * HEAD_DIM + d] - O / L;
  }
}

extern "C" void kernel_launch(void* const* d_in, const int* in_sizes, int n_in,
                              void* d_out, int out_size, void* d_ws, size_t ws_size,
                              hipStream_t stream) {
  const float* x   = (const float*)d_in[0];
  const int*   adj = (const int*)d_in[1];
  const float* Wq  = (const float*)d_in[2];
  const float* bq  = (const float*)d_in[3];
  const float* Wk  = (const float*)d_in[4];
  const float* bk  = (const float*)d_in[5];
  const float* Wv  = (const float*)d_in[6];
  const float* bv  = (const float*)d_in[7];
  float* out = (float*)d_out;

  char* ws = (char*)d_ws;
  ushort_t*     Qph  = (ushort_t*)(ws);                          // 2 MB
  ushort_t*     Qpl  = (ushort_t*)(ws + ((size_t)2  << 20));     // 2 MB
  ushort_t*     Kph  = (ushort_t*)(ws + ((size_t)4  << 20));     // 2 MB
  ushort_t*     Kpl  = (ushort_t*)(ws + ((size_t)6  << 20));     // 2 MB
  ushort_t*     SVph = (ushort_t*)(ws + ((size_t)8  << 20));     // 2 MB
  ushort_t*     SVpl = (ushort_t*)(ws + ((size_t)10 << 20));     // 2 MB
  float*        V    = (float*)(ws + ((size_t)12 << 20));        // 4 MB
  unsigned int* bits = (unsigned int*)(ws + ((size_t)16 << 20)); // 2 MB
  ushort_t*     xph  = (ushort_t*)(ws + ((size_t)18 << 20));     // 2 MB
  ushort_t*     xpl  = (ushort_t*)(ws + ((size_t)20 << 20));     // 2 MB
  ushort_t*     Wph  = (ushort_t*)(ws + ((size_t)22 << 20));           // 384 KB
  ushort_t*     Wpl  = (ushort_t*)(ws + ((size_t)22 << 20) + 393216);  // 384 KB

  pack_adj<<<dim3(N_NODES), 256, 0, stream>>>(adj, bits);
  split_x<<<dim3(512), 256, 0, stream>>>(x, xph, xpl);
  split_w<<<dim3(96), 256, 0, stream>>>(Wq, Wk, Wv, Wph, Wpl);
  qkv_mfma<<<dim3(N_NODES / 32, 6), 256, 0, stream>>>(
      xph, xpl, Wph, Wpl, bq, bk, bv, Qph, Qpl, Kph, Kpl, V);
  sv_softmax_t<<<dim3(N_NODES / 32), 256, 0, stream>>>(V, SVph, SVpl);
  attn32<<<dim3(N_NODES / 32, HEADS), 512, 0, stream>>>(
      Qph, Qpl, Kph, Kpl, SVph, SVpl, bits, V, out);
}